// Round 6
// baseline (213.799 us; speedup 1.0000x reference)
//
#include <hip/hip_runtime.h>
#include <hip/hip_bf16.h>
#include <math.h>

// PillarHist: per-row 64-bin hist (count/mean_z/mean_r interleaved) -> Linear(192->64) -> BN(train) -> ReLU
// ABLATION SPLIT (R6): k1 divided into two harness-timed kernels to localize the ~45-50 us wall
// that survived occupancy/pipelining/load-pattern changes (R1-R5, all pipes <25% busy).
// k0 (16 blocks): permuted bf16 B-fragments into d_ws + zero BN totals.
// k1a (6250 blocks, 128 thr = one wave pair, 16 rows): load z/r (uint2) -> LDS u64-packed hist
//     (ONE ds_add_u64/point) -> pair barrier -> decode bin-group h per wave (planes {h,2+h,4+h})
//     -> store decoded bf16 A-fragments to workspace (3 coalesced 1-KB stores/wave). No B, no BN.
// k1b (512 blocks, 256 thr, grid-stride): pure GEMM. Per 16-row tile: 6 coalesced A-frag loads
//     (double-buffered across tiles), 24 MFMAs (s order 0,2,4,1,3,5 = bit-identical to R5),
//     bias + x store + BN fixed-point partials (order-independent u64 atomics).
// k3: sum replicas -> scale/shift -> apply BN+ReLU in-place (grid-stride).

typedef __attribute__((ext_vector_type(8))) short bf16x8;   // 8 bf16 = 4 VGPRs = 16 B
typedef __attribute__((ext_vector_type(4))) float f32x4;
typedef __attribute__((ext_vector_type(4))) int   i32x4;

#define ZMINF   (-3.0f)
#define INV_BIN 16.0f            // 1/BIN_SIZE (exact pow2)
#define QS      8192.0f          // 2^13 payload scale
#define INV_QS  (1.0f / 8192.0f)
#define PBIASF  65536.0f         // 2^16 payload bias (covers |z|<8; 64*max_payload < 2^24)
#define PBIASI  65536
#define CBIT    16777216         // 2^24 count increment (hi word only)
#define TSC     16777216.0f     // 2^24 fixed-point scale for BN totals
#define INV_TSC (1.0f / 16777216.0f)
#define REPS    16               // BN total replicas
#define RSTRIDE 66               // u64 per row (64 bins + 2 pad -> bank spread)

__device__ __forceinline__ short f2bf(float f) {
    __hip_bfloat16 h = __float2bfloat16(f);   // RNE
    return __builtin_bit_cast(short, h);
}

// ---- k0: grid-stride. Permuted W -> bf16 fragments (frag-major [s*4+t][lane][j]) + zero totals ----
__global__ __launch_bounds__(256)
void k0_prep(const float* __restrict__ W,                  // [64,192]
             short*       __restrict__ wsW,                // [24*64*8] bf16
             unsigned long long* __restrict__ totals)      // [REPS*128]
{
    const int tid    = blockIdx.x * 256 + threadIdx.x;
    const int stride = gridDim.x * 256;
    for (int e = tid; e < 24 * 64 * 8; e += stride) {
        const int j  = e & 7;
        const int ln = (e >> 3) & 63;
        const int st = e >> 9;                       // s*4+t
        const int s  = st >> 2, t = st & 3;
        const int k  = s * 32 + (ln >> 4) * 8 + j;   // planar k
        const int n  = t * 16 + (ln & 15);           // output channel
        const int wc = (k < 64) ? 3 * k
                     : (k < 128) ? 3 * (k - 64) + 1
                                 : 3 * (k - 128) + 2;
        wsW[e] = f2bf(W[n * 192 + wc]);
    }
    for (int e = tid; e < REPS * 128; e += stride) totals[e] = 0ull;
}

// ---- k1a: hist build + fragment decode + streamout (NO MFMA, NO B, NO BN) ----
__global__ __launch_bounds__(128, 8)
void k1a_hist(const uint2* __restrict__ feat2,   // zw of (row,pt) at (row*64+pt)*2+1
              const int*   __restrict__ nump,    // [M]
              bf16x8*      __restrict__ Ap,      // [nblk][6][64] decoded A-fragments
              int M)
{
    __shared__ unsigned long long sH[16 * RSTRIDE];   // 8448 B

    const int tid  = threadIdx.x;
    const int half = tid >> 6;          // wave 0/1: owns rows half*8.., decodes bin-group half
    const int lane = tid & 63;
    const int col  = lane & 15;
    const int quad = lane >> 4;

    const int blk   = blockIdx.x;
    const int gbase = blk * 16;

    // ---- 8 rows of z/r per wave in ONE load batch (uint2 = 8 B/lane; 16 VGPRs) ----
    uint2 zw[8];
    const int npv = nump[min(gbase + half * 8 + (lane & 7), M - 1)];  // lanes 0..7 hold own rows
    #pragma unroll
    for (int uu = 0; uu < 8; ++uu) {
        const int rc = min(gbase + half * 8 + uu, M - 1);
        zw[uu] = feat2[((size_t)rc * 64 + lane) * 2 + 1];
    }

    // ---- zero OWN 8-row strip (8*66 u64 = 4224 B); overlaps load latency ----
    {
        i32x4* p4 = (i32x4*)&sH[(size_t)half * 8 * RSTRIDE];
        #pragma unroll
        for (int i = 0; i < 5; ++i) {
            const int idx = lane + i * 64;
            if (idx < (8 * RSTRIDE * 2) / 4) p4[idx] = i32x4{0, 0, 0, 0};
        }
    }
    __builtin_amdgcn_wave_barrier();

    // ---- packed hist, own 8 rows: ONE native ds_add_u64 per point ----
    #pragma unroll
    for (int uu = 0; uu < 8; ++uu) {
        const int u = half * 8 + uu;
        int np_u = __builtin_amdgcn_readlane(npv, uu);
        np_u = (gbase + u < M) ? np_u : 0;                   // uniform tail guard
        if (lane < np_u) {
            const float z  = __int_as_float((int)zw[uu].x);
            const float rr = __int_as_float((int)zw[uu].y);
            int bi = (int)((z - ZMINF) * INV_BIN);           // trunc, matches astype(int32)
            bi = min(max(bi, 0), 63);
            const unsigned long long add =
                ((unsigned long long)(unsigned)(CBIT + PBIASI + (int)(z * QS)) << 32)
                | (unsigned)(PBIASI + (int)(rr * QS));
            atomicAdd(&sH[u * RSTRIDE + bi], add);
        }
    }

    __syncthreads();   // pair-exact: partner's 8 rows complete & visible

    // ---- decode bin-group g = half: bins half*32 + quad*8 .. +7 of row col ----
    const int* ar = (const int*)sH + col * (RSTRIDE * 2);
    const int o0 = half * 32 + quad * 8;
    const i32x4* apt = (const i32x4*)(ar + 2 * o0);          // 64 B contiguous: 8 bins (r,z)x4
    const i32x4 a0 = apt[0], a1 = apt[1], a2 = apt[2], a3 = apt[3];
    const int zz[8]  = {a0.y, a0.w, a1.y, a1.w, a2.y, a2.w, a3.y, a3.w};
    const int rrw[8] = {a0.x, a0.z, a1.x, a1.z, a2.x, a2.z, a3.x, a3.z};
    float cnt[8], rcp[8];
    bf16x8 af_c, af_z, af_r;
    #pragma unroll
    for (int j = 0; j < 8; ++j) {
        cnt[j] = (float)(zz[j] >> 24);
        af_c[j] = f2bf(cnt[j]);
    }
    #pragma unroll
    for (int j = 0; j < 8; ++j) {
        rcp[j] = __builtin_amdgcn_rcpf(cnt[j] + 1e-5f) * INV_QS;
        const float pay = (float)(zz[j] & 0xFFFFFF);         // exact (<2^24)
        af_z[j] = f2bf((pay - cnt[j] * PBIASF) * rcp[j]);
    }
    #pragma unroll
    for (int j = 0; j < 8; ++j)
        af_r[j] = f2bf(((float)rrw[j] - cnt[j] * PBIASF) * rcp[j]);

    // ---- streamout: fragment-major [blk][s][lane]; s = half, 2+half, 4+half ----
    bf16x8* dst = Ap + (size_t)blk * 6 * 64;
    dst[(0 + half) * 64 + lane] = af_c;
    dst[(2 + half) * 64 + lane] = af_z;
    dst[(4 + half) * 64 + lane] = af_r;
}

// ---- k1b: pure streaming GEMM from decoded fragments ----
__global__ __launch_bounds__(256, 2)
void k1b_gemm(const bf16x8* __restrict__ Ap,     // [nblk][6][64]
              const bf16x8* __restrict__ wsWf,   // [24*64] B fragments (L2-hot)
              const float*  __restrict__ bvec,   // [64]
              float*        __restrict__ xout,   // [M,64]
              unsigned long long* __restrict__ totals, // [REPS*128]
              int M, int nblk)
{
    const int tid  = threadIdx.x;
    const int wave = tid >> 6;
    const int lane = tid & 63;
    const int col  = lane & 15;
    const int quad = lane >> 4;

    const int gw = blockIdx.x * 4 + wave;
    const int nw = gridDim.x * 4;

    // ---- B fragments + bias loaded ONCE per wave ----
    bf16x8 bfr[6][4];
    #pragma unroll
    for (int p = 0; p < 6; ++p)
        #pragma unroll
        for (int t = 0; t < 4; ++t)
            bfr[p][t] = wsWf[(p * 4 + t) * 64 + lane];
    float bias[4];
    #pragma unroll
    for (int t = 0; t < 4; ++t) bias[t] = bvec[t * 16 + col];

    float psum[4] = {0.f, 0.f, 0.f, 0.f};
    float psq[4]  = {0.f, 0.f, 0.f, 0.f};

    int blk = gw;
    bf16x8 a[6];
    if (blk < nblk) {
        const bf16x8* ap = Ap + (size_t)blk * 6 * 64 + lane;
        #pragma unroll
        for (int s = 0; s < 6; ++s) a[s] = ap[s * 64];
    }

    while (blk < nblk) {
        const int nxt = blk + nw;
        bf16x8 an[6];
        if (nxt < nblk) {   // prefetch next tile's fragments (latency hides under MFMA+epilogue)
            const bf16x8* ap = Ap + (size_t)nxt * 6 * 64 + lane;
            #pragma unroll
            for (int s = 0; s < 6; ++s) an[s] = ap[s * 64];
        }

        // ---- 24 MFMAs; s order {0,2,4,1,3,5} bit-identical to the fused kernel ----
        f32x4 acc[4] = {};
        #pragma unroll
        for (int so = 0; so < 6; ++so) {
            const int s = (so < 3) ? (so * 2) : ((so - 3) * 2 + 1);   // 0,2,4,1,3,5
            #pragma unroll
            for (int t = 0; t < 4; ++t)
                acc[t] = __builtin_amdgcn_mfma_f32_16x16x32_bf16(a[s], bfr[s][t], acc[t], 0, 0, 0);
        }

        // ---- epilogue: +bias, store x, BN partials. C/D: col=lane&15, row=quad*4+i ----
        const int gbase = blk * 16;
        #pragma unroll
        for (int i = 0; i < 4; ++i) {
            const int row = gbase + quad * 4 + i;
            if (row < M) {
                float* xr = xout + (size_t)row * 64 + col;
                #pragma unroll
                for (int t = 0; t < 4; ++t) {
                    const float xv = acc[t][i] + bias[t];
                    xr[t * 16] = xv;
                    psum[t] += xv;
                    psq[t]  += xv * xv;
                }
            }
        }

        #pragma unroll
        for (int s = 0; s < 6; ++s) a[s] = an[s];
        blk = nxt;
    }

    // ---- BN partials: reduce over quads; lane's channel = quad*16+col = lane ----
    #pragma unroll
    for (int t = 0; t < 4; ++t) {
        psum[t] += __shfl_xor(psum[t], 16);
        psum[t] += __shfl_xor(psum[t], 32);
        psq[t]  += __shfl_xor(psq[t], 16);
        psq[t]  += __shfl_xor(psq[t], 32);
    }
    float myS = psum[0], myQ = psq[0];
    if (quad == 1) { myS = psum[1]; myQ = psq[1]; }
    if (quad == 2) { myS = psum[2]; myQ = psq[2]; }
    if (quad == 3) { myS = psum[3]; myQ = psq[3]; }
    unsigned long long* dst = totals + (gw & (REPS - 1)) * 128 + lane;
    atomicAdd(dst,      (unsigned long long)(long long)(myS * TSC));
    atomicAdd(dst + 64, (unsigned long long)(long long)(myQ * TSC));
}

__global__ __launch_bounds__(256)
void k3_bn_apply(float4* __restrict__ x,
                 const unsigned long long* __restrict__ totals,
                 const float* __restrict__ gamma,
                 const float* __restrict__ beta,
                 float invM, int n4)
{
    __shared__ float sT[128];
    __shared__ float sa[64];
    __shared__ float sc[64];
    const int t = threadIdx.x;
    if (t < 128) {   // sum replicas: deterministic across blocks
        long long s = 0;
        #pragma unroll
        for (int rep = 0; rep < REPS; ++rep) s += (long long)totals[rep * 128 + t];
        sT[t] = (float)s * (invM * INV_TSC);
    }
    __syncthreads();
    if (t < 64) {
        const float mu   = sT[t];
        const float q    = sT[64 + t];
        const float var  = q - mu * mu;
        const float rstd = 1.0f / sqrtf(var + 1e-5f);
        const float a    = gamma[t] * rstd;
        sa[t] = a;
        sc[t] = beta[t] - mu * a;
    }
    __syncthreads();
    const int stride = gridDim.x * 256;
    for (int i = blockIdx.x * 256 + t; i < n4; i += stride) {
        const float4 a = ((const float4*)sa)[i & 15];   // 64 ch = 16 float4
        const float4 c = ((const float4*)sc)[i & 15];
        float4 v = x[i];
        v.x = fmaxf(fmaf(v.x, a.x, c.x), 0.f);
        v.y = fmaxf(fmaf(v.y, a.y, c.y), 0.f);
        v.z = fmaxf(fmaf(v.z, a.z, c.z), 0.f);
        v.w = fmaxf(fmaf(v.w, a.w, c.w), 0.f);
        x[i] = v;
    }
}

extern "C" void kernel_launch(void* const* d_in, const int* in_sizes, int n_in,
                              void* d_out, int out_size, void* d_ws, size_t ws_size,
                              hipStream_t stream) {
    const uint2*  feat2 = (const uint2*)d_in[0];   // [M,64,4] fp32 viewed as uint2 pairs
    const int*    nump  = (const int*)d_in[1];     // [M]
    // d_in[2] = coors (unused)
    const float*  W     = (const float*)d_in[3];   // [64,192]
    const float*  bvec  = (const float*)d_in[4];   // [64]
    const float*  gamma = (const float*)d_in[5];   // [64]
    const float*  beta  = (const float*)d_in[6];   // [64]

    const int M = in_sizes[1];
    float* xout = (float*)d_out;
    short* wsW  = (short*)d_ws;                                   // [24*64*8] bf16 B-fragments
    unsigned long long* totals =
        (unsigned long long*)((char*)d_ws + 24 * 64 * 8 * sizeof(short));  // [REPS*128] u64
    bf16x8* Ap =
        (bf16x8*)((char*)d_ws + 24 * 64 * 8 * sizeof(short) + REPS * 128 * 8); // [nblk][6][64]

    const int nblk = (M + 15) / 16;

    k0_prep<<<16, 256, 0, stream>>>(W, wsW, totals);

    k1a_hist<<<nblk, 128, 0, stream>>>(feat2, nump, Ap, M);

    k1b_gemm<<<512, 256, 0, stream>>>(Ap, (const bf16x8*)wsW, bvec, xout, totals, M, nblk);

    const int n4 = out_size / 4;
    const int nblk3 = (n4 + 256 * 16 - 1) / (256 * 16);
    k3_bn_apply<<<nblk3, 256, 0, stream>>>((float4*)d_out, totals, gamma, beta,
                                           1.0f / (float)M, n4);
}